// Round 14
// baseline (251.147 us; speedup 1.0000x reference)
//
#include <hip/hip_runtime.h>

// B=4, S=2048, D=1024. out = softmax((x@Wk)(x@Wq)^T / 32) @ (x@Wv), fp32 out.
// Algebra: Gt[e,d] = Wq[e,:]·Wk[d,:]; y = x·G; scores = y·x^T (B^T GEMMs).
// GEMM core: r6 128x128 / 4-wave / BK=64 / 2-deep counted-vmcnt pipeline,
// but B operand loaded DIRECTLY global->VGPR (L2-resident panels), A via
// swizzled LDS. Halves LDS-read pressure (was 1.24x the MFMA pipe).
// scores writes exp(s/32) bf16 P; pv row-sums via ones-MFMA.

typedef __attribute__((ext_vector_type(8))) short bf16x8;
typedef __attribute__((ext_vector_type(4))) float f32x4;

__device__ __forceinline__ unsigned short f2bf(float f) {
    unsigned int u = __float_as_uint(f);
    u += 0x7fff + ((u >> 16) & 1);   // RNE
    return (unsigned short)(u >> 16);
}

__device__ __forceinline__ void gld_lds16(const unsigned short* g, unsigned short* l) {
    __builtin_amdgcn_global_load_lds(
        (const __attribute__((address_space(1))) void*)g,
        (__attribute__((address_space(3))) void*)l, 16, 0, 0);
}

template<int N> __device__ __forceinline__ void vmcnt_wait() {
    if constexpr (N == 0)  asm volatile("s_waitcnt vmcnt(0)"  ::: "memory");
    else if constexpr (N == 8)  asm volatile("s_waitcnt vmcnt(8)"  ::: "memory");
    else if constexpr (N == 12) asm volatile("s_waitcnt vmcnt(12)" ::: "memory");
}
__device__ __forceinline__ void bar() {
    asm volatile("" ::: "memory");
    __builtin_amdgcn_s_barrier();
    asm volatile("" ::: "memory");
}

// ---------------- 128x128x(64*KT) bf16 B^T GEMM, 4 waves (2x2) ----------------
// A: LDS-staged (2 buf x 2 kh x [128][32] bf16, XOR-swizzled, gld_lds direct).
// B: global->VGPR per-lane fragment loads (L2-resident panel), double-buffered
// one K-tile ahead in registers (b0/b1, static indexing via manual 2-unroll).
// Steady-state wait: vmcnt(12) = A(kt+1)[4] oldest of {A(kt+1)4, B(kt+1)8, A(kt+2)4}.
template<int KT, bool RS>
__device__ __forceinline__ void gemm4b(
    const unsigned short* __restrict__ A, const unsigned short* __restrict__ B,
    int lda, int ldb, int bm, int bn,
    unsigned short* As,
    f32x4 (&acc)[4][4], f32x4 (&os)[4])
{
    static_assert(KT % 2 == 0, "KT must be even");
    const int tid  = threadIdx.x;
    const int lane = tid & 63;
    const int wave = tid >> 6;            // 0..3
    const int wr = wave >> 1, wc = wave & 1;
    const int lr = lane & 15, kg = lane >> 4;

    const bf16x8 ONES = { (short)0x3F80, (short)0x3F80, (short)0x3F80, (short)0x3F80,
                          (short)0x3F80, (short)0x3F80, (short)0x3F80, (short)0x3F80 };

    // A staging map (as r6): thread t -> row t>>2, phys unit t&3;
    // global source unit = (t&3) ^ ((t>>3)&3)  (inverse of read swizzle)
    const int srow = tid >> 2;
    const int ssrc = ((tid & 3) ^ ((tid >> 3) & 3)) * 8;
    const unsigned short* pa0 = A + (size_t)(bm + srow) * lda + ssrc;
    const unsigned short* pa1 = A + (size_t)(bm + 64 + srow) * lda + ssrc;

    const int phys = (kg ^ ((lr >> 1) & 3)) * 8;
    const int aoff = (wr * 64 + lr) * 32 + phys;

    // B direct per-lane fragment pointers: row = bn + wc*64 + nf*16 + lr, k base kg*8
    const unsigned short* pB0 = B + (size_t)(bn + wc * 64 +  0 + lr) * ldb + kg * 8;
    const unsigned short* pB1 = B + (size_t)(bn + wc * 64 + 16 + lr) * ldb + kg * 8;
    const unsigned short* pB2 = B + (size_t)(bn + wc * 64 + 32 + lr) * ldb + kg * 8;
    const unsigned short* pB3 = B + (size_t)(bn + wc * 64 + 48 + lr) * ldb + kg * 8;

    auto stageA = [&](int buf, int kt) {
        unsigned short* da = As + buf * 8192 + wave * 512;
        #pragma unroll
        for (int kh = 0; kh < 2; kh++) {
            const int go = kt * 64 + kh * 32;
            gld_lds16(pa0 + go, da + kh * 4096);
            gld_lds16(pa1 + go, da + kh * 4096 + 2048);
        }
    };

    typedef bf16x8 Bfrag[4][2];
    auto loadB = [&](Bfrag& d, int kt) {
        #pragma unroll
        for (int kh = 0; kh < 2; kh++) {
            const int go = kt * 64 + kh * 32;
            d[0][kh] = *reinterpret_cast<const bf16x8*>(pB0 + go);
            d[1][kh] = *reinterpret_cast<const bf16x8*>(pB1 + go);
            d[2][kh] = *reinterpret_cast<const bf16x8*>(pB2 + go);
            d[3][kh] = *reinterpret_cast<const bf16x8*>(pB3 + go);
        }
    };

    auto comp = [&](int buf, Bfrag& bf) {
        const unsigned short* Ab = As + buf * 8192 + aoff;
        #pragma unroll
        for (int kh = 0; kh < 2; kh++) {
            bf16x8 af[4];
            #pragma unroll
            for (int mf = 0; mf < 4; mf++)
                af[mf] = *reinterpret_cast<const bf16x8*>(Ab + kh * 4096 + mf * 512);
            __builtin_amdgcn_s_setprio(1);
            #pragma unroll
            for (int mf = 0; mf < 4; mf++)
                #pragma unroll
                for (int nf = 0; nf < 4; nf++)
                    acc[mf][nf] = __builtin_amdgcn_mfma_f32_16x16x32_bf16(af[mf], bf[nf][kh], acc[mf][nf], 0, 0, 0);
            if constexpr (RS) {
                #pragma unroll
                for (int mf = 0; mf < 4; mf++)
                    os[mf] = __builtin_amdgcn_mfma_f32_16x16x32_bf16(af[mf], ONES, os[mf], 0, 0, 0);
            }
            __builtin_amdgcn_s_setprio(0);
        }
    };

    Bfrag b0, b1;

    // prologue: A tiles 0,1 staged (8 loads), B tile 0 in regs (8 loads)
    stageA(0, 0);
    stageA(1, 1);
    loadB(b0, 0);
    vmcnt_wait<12>();          // A(0) = oldest 4 of 16 landed (b0 compiler-waited at use)
    bar();

    for (int kt = 0; kt < KT; kt += 2) {
        // ---- even iter: buf 0, frags b0 ----
        if (kt + 1 < KT) loadB(b1, kt + 1);
        comp(0, b0);
        bar();                                   // all waves done reading A buf 0
        if (kt + 2 < KT) { stageA(0, kt + 2); vmcnt_wait<12>(); }  // A(kt+1) landed
        else             { vmcnt_wait<8>(); }    // kt==KT-2: A(KT-1) landed (B(KT-1) newer 8)
        bar();                                   // A buf 1 globally ready

        // ---- odd iter: buf 1, frags b1 ----
        const int k1 = kt + 1;
        if (k1 + 1 < KT) loadB(b0, k1 + 1);
        comp(1, b1);
        if (k1 == KT - 1) break;
        bar();
        stageA(1, k1 + 2);                        // k1+2 <= KT-1 here (KT even)
        vmcnt_wait<12>();                         // A(k1+1) landed
        bar();
    }
}

// ================ stage 1 (merged): g_gemm | convert_x | transpose_wv ================
// blocks [0,256):      Gt[m,n] = sum_j Wq[m,j]*Wk[n,j]  (64x64 tiles, reg-prefetch)
// blocks [256,4352):   x f32 -> xb bf16
// blocks [4352,4608):  Wv [k][n] f32 -> wvT [n][k] bf16
__global__ __launch_bounds__(256) void stage1(
    const float* __restrict__ x,  unsigned short* __restrict__ xb,
    const float* __restrict__ wv, unsigned short* __restrict__ wvT,
    const float* __restrict__ wq, const float* __restrict__ wk,
    unsigned short* __restrict__ Gt)
{
    __shared__ unsigned short SM[4608];
    const int bid = blockIdx.x;
    const int tid = threadIdx.x;

    if (bid >= 256 && bid < 4352) {
        const size_t idx = (size_t)(bid - 256) * 256 + tid;
        const float4* xi = reinterpret_cast<const float4*>(x) + idx * 2;
        float4 v0 = xi[0], v1 = xi[1];
        ushort4 a = { f2bf(v0.x), f2bf(v0.y), f2bf(v0.z), f2bf(v0.w) };
        ushort4 b = { f2bf(v1.x), f2bf(v1.y), f2bf(v1.z), f2bf(v1.w) };
        ushort4* xo = reinterpret_cast<ushort4*>(xb) + idx * 2;
        xo[0] = a; xo[1] = b;
        return;
    }
    if (bid >= 4352) {
        auto T = reinterpret_cast<unsigned short (*)[72]>(SM);
        const int tb = bid - 4352;
        const int k0 = (tb >> 4) * 64, n0 = (tb & 15) * 64;
        const int r = tid >> 4, c4 = (tid & 15) * 4;
        #pragma unroll
        for (int i = 0; i < 4; i++) {
            int kr = r + i * 16;
            float4 v = *reinterpret_cast<const float4*>(&wv[(size_t)(k0 + kr) * 1024 + n0 + c4]);
            T[c4 + 0][kr] = f2bf(v.x);
            T[c4 + 1][kr] = f2bf(v.y);
            T[c4 + 2][kr] = f2bf(v.z);
            T[c4 + 3][kr] = f2bf(v.w);
        }
        __syncthreads();
        #pragma unroll
        for (int i = 0; i < 4; i++) {
            int n = r + i * 16;
            ushort4 v = *reinterpret_cast<const ushort4*>(&T[n][c4]);
            *reinterpret_cast<ushort4*>(&wvT[(size_t)(n0 + n) * 1024 + k0 + c4]) = v;
        }
        return;
    }

    // g_gemm: 64x64 tile, BK=32, reg-prefetch pipelined, f32->bf16 in staging
    unsigned short* As = SM;
    unsigned short* Bs = SM + 2048;
    const int gb = bid;
    const int bm = (gb >> 4) * 64, bn = (gb & 15) * 64;

    const int lane = tid & 63;
    const int wave = tid >> 6;
    const int wr = wave >> 1, wc = wave & 1;
    const int lr = lane & 15, kg = lane >> 4;

    const int srow = tid >> 2;
    const int su   = tid & 3;
    const int sphys = (su ^ ((srow >> 1) & 3)) * 8;
    const int rphys = (kg ^ ((lr >> 1) & 3)) * 8;
    const int aoff = (wr * 32 + lr) * 32 + rphys;
    const int boff = (wc * 32 + lr) * 32 + rphys;

    const float* pa = &wq[(size_t)(bm + srow) * 1024 + su * 8];
    const float* pb = &wk[(size_t)(bn + srow) * 1024 + su * 8];

    f32x4 acc[2][2] = {};

    float4 a0 = *reinterpret_cast<const float4*>(pa);
    float4 a1 = *reinterpret_cast<const float4*>(pa + 4);
    float4 b0 = *reinterpret_cast<const float4*>(pb);
    float4 b1 = *reinterpret_cast<const float4*>(pb + 4);

    for (int k0 = 0; k0 < 1024; k0 += 32) {
        ushort4 u0 = { f2bf(a0.x), f2bf(a0.y), f2bf(a0.z), f2bf(a0.w) };
        ushort4 u1 = { f2bf(a1.x), f2bf(a1.y), f2bf(a1.z), f2bf(a1.w) };
        *reinterpret_cast<ushort4*>(&As[srow * 32 + sphys])     = u0;
        *reinterpret_cast<ushort4*>(&As[srow * 32 + sphys + 4]) = u1;
        ushort4 t0 = { f2bf(b0.x), f2bf(b0.y), f2bf(b0.z), f2bf(b0.w) };
        ushort4 t1 = { f2bf(b1.x), f2bf(b1.y), f2bf(b1.z), f2bf(b1.w) };
        *reinterpret_cast<ushort4*>(&Bs[srow * 32 + sphys])     = t0;
        *reinterpret_cast<ushort4*>(&Bs[srow * 32 + sphys + 4]) = t1;

        if (k0 + 32 < 1024) {
            const float* npa = pa + k0 + 32;
            const float* npb = pb + k0 + 32;
            a0 = *reinterpret_cast<const float4*>(npa);
            a1 = *reinterpret_cast<const float4*>(npa + 4);
            b0 = *reinterpret_cast<const float4*>(npb);
            b1 = *reinterpret_cast<const float4*>(npb + 4);
        }
        __syncthreads();

        bf16x8 af[2], bf[2];
        #pragma unroll
        for (int mf = 0; mf < 2; mf++)
            af[mf] = *reinterpret_cast<const bf16x8*>(&As[aoff + mf * 512]);
        #pragma unroll
        for (int nf = 0; nf < 2; nf++)
            bf[nf] = *reinterpret_cast<const bf16x8*>(&Bs[boff + nf * 512]);
        #pragma unroll
        for (int mf = 0; mf < 2; mf++)
            #pragma unroll
            for (int nf = 0; nf < 2; nf++)
                acc[mf][nf] = __builtin_amdgcn_mfma_f32_16x16x32_bf16(af[mf], bf[nf], acc[mf][nf], 0, 0, 0);
        __syncthreads();
    }
    #pragma unroll
    for (int mf = 0; mf < 2; mf++)
        #pragma unroll
        for (int nf = 0; nf < 2; nf++)
            #pragma unroll
            for (int r = 0; r < 4; r++)
                Gt[(size_t)(bm + wr * 32 + mf * 16 + kg * 4 + r) * 1024
                   + bn + wc * 32 + nf * 16 + lr] = f2bf(acc[mf][nf][r]);
}

// ---------------- projections: z=0: y = x·G; z=1: vvT (transposed). grid 1024 ----------------
__global__ __launch_bounds__(256, 2) void proj_gemm(
    const unsigned short* __restrict__ xb, const unsigned short* __restrict__ Gt,
    const unsigned short* __restrict__ wvT,
    unsigned short* __restrict__ y, unsigned short* __restrict__ vvT)
{
    __shared__ unsigned short As[2 * 128 * 64];   // 32 KB
    const int bid = blockIdx.x;
    const int wg  = (bid & 7) * 128 + (bid >> 3);   // 1024 % 8 == 0, bijective
    const int z   = wg >> 9;
    const int rem = wg & 511;
    const int bm  = (rem >> 3) * 128;
    const int bn  = (rem & 7) * 128;
    const unsigned short* Bw = z ? wvT : Gt;

    f32x4 acc[4][4] = {};
    f32x4 os[4] = {};
    gemm4b<16, false>(xb, Bw, 1024, 1024, bm, bn, As, acc, os);

    const int tid = threadIdx.x, lane = tid & 63, wave = tid >> 6;
    const int wr = wave >> 1, wc = wave & 1, lr = lane & 15, kg = lane >> 4;
    if (z == 0) {
        #pragma unroll
        for (int mf = 0; mf < 4; mf++)
            #pragma unroll
            for (int nf = 0; nf < 4; nf++)
                #pragma unroll
                for (int r = 0; r < 4; r++)
                    y[(size_t)(bm + wr * 64 + mf * 16 + kg * 4 + r) * 1024
                      + bn + wc * 64 + nf * 16 + lr] = f2bf(acc[mf][nf][r]);
    } else {
        const int batch = bm >> 11;                 // 128-tiles never span batches
        unsigned short* o = vvT + (size_t)batch * 1024 * 2048;
        #pragma unroll
        for (int mf = 0; mf < 4; mf++)
            #pragma unroll
            for (int nf = 0; nf < 4; nf++) {
                ushort4 v = { f2bf(acc[mf][nf][0]), f2bf(acc[mf][nf][1]),
                              f2bf(acc[mf][nf][2]), f2bf(acc[mf][nf][3]) };
                *reinterpret_cast<ushort4*>(
                    &o[(size_t)(bn + wc * 64 + nf * 16 + lr) * 2048
                       + (bm & 2047) + wr * 64 + mf * 16 + kg * 4]) = v;
            }
    }
}

// ---------------- scores: y[b]·xb[b]^T / 32, exp epilogue -> bf16 P. grid 1024 ----------------
__global__ __launch_bounds__(256, 2) void scores_gemm(
    const unsigned short* __restrict__ y, const unsigned short* __restrict__ xb,
    unsigned short* __restrict__ P)
{
    __shared__ unsigned short As[2 * 128 * 64];   // 32 KB
    const int bid = blockIdx.x;
    const int wg  = (bid & 7) * 128 + (bid >> 3);   // 1024 % 8 == 0
    const int z   = wg >> 8;
    const int rem = wg & 255;
    const int bm  = (rem >> 4) * 128;
    const int bn  = (rem & 15) * 128;
    const unsigned short* A = y  + (size_t)z * 2048 * 1024;
    const unsigned short* B = xb + (size_t)z * 2048 * 1024;
    unsigned short* out = P + (size_t)z * 2048 * 2048;

    f32x4 acc[4][4] = {};
    f32x4 os[4] = {};
    gemm4b<16, false>(A, B, 1024, 1024, bm, bn, As, acc, os);

    const int tid = threadIdx.x, lane = tid & 63, wave = tid >> 6;
    const int wr = wave >> 1, wc = wave & 1, lr = lane & 15, kg = lane >> 4;
    #pragma unroll
    for (int mf = 0; mf < 4; mf++)
        #pragma unroll
        for (int nf = 0; nf < 4; nf++)
            #pragma unroll
            for (int r = 0; r < 4; r++)
                out[(size_t)(bm + wr * 64 + mf * 16 + kg * 4 + r) * 2048
                    + bn + wc * 64 + nf * 16 + lr]
                    = f2bf(__expf(acc[mf][nf][r] * 0.03125f));
}

// ---------------- PV: 128x128 tiles, K=2048, grid 512; ones-MFMA row-sums; out = acc/l ----------------
__global__ __launch_bounds__(256, 2) void pv_gemm(
    const unsigned short* __restrict__ P, const unsigned short* __restrict__ vvT,
    float* __restrict__ out)
{
    __shared__ unsigned short As[2 * 128 * 64];   // 32 KB
    const int bid = blockIdx.x;
    const int wg  = (bid & 7) * 64 + (bid >> 3);    // 512 % 8 == 0
    const int z   = wg >> 7;
    const int rem = wg & 127;
    const int bm  = (rem >> 3) * 128;
    const int bn  = (rem & 7) * 128;
    const unsigned short* A = P   + (size_t)z * 2048 * 2048;
    const unsigned short* B = vvT + (size_t)z * 1024 * 2048;
    float* o = out + (size_t)z * 2048 * 1024;

    f32x4 acc[4][4] = {};
    f32x4 os[4] = {};
    gemm4b<32, true>(A, B, 2048, 2048, bm, bn, As, acc, os);

    const int tid = threadIdx.x, lane = tid & 63, wave = tid >> 6;
    const int wr = wave >> 1, wc = wave & 1, lr = lane & 15, kg = lane >> 4;

    // os[mf][r] = full row-sum for row (bm + wr*64 + mf*16 + kg*4 + r), lane-replicated.
    #pragma unroll
    for (int mf = 0; mf < 4; mf++)
        #pragma unroll
        for (int r = 0; r < 4; r++) {
            const float inv = 1.0f / os[mf][r];
            #pragma unroll
            for (int nf = 0; nf < 4; nf++)
                o[(size_t)(bm + wr * 64 + mf * 16 + kg * 4 + r) * 1024
                  + bn + wc * 64 + nf * 16 + lr] = acc[mf][nf][r] * inv;
        }
}

extern "C" void kernel_launch(void* const* d_in, const int* in_sizes, int n_in,
                              void* d_out, int out_size, void* d_ws, size_t ws_size,
                              hipStream_t stream) {
    const float* x  = (const float*)d_in[0];
    const float* wk = (const float*)d_in[1];
    const float* wq = (const float*)d_in[2];
    const float* wv = (const float*)d_in[3];
    float* out = (float*)d_out;

    char* ws = (char*)d_ws;
    const size_t MB = 1024 * 1024;
    unsigned short* xb  = (unsigned short*)(ws);             // 16MB  x bf16
    unsigned short* y   = (unsigned short*)(ws + 16 * MB);   // 16MB  x·G bf16
    unsigned short* Gt  = (unsigned short*)(ws + 32 * MB);   // 2MB   Gt[e,d]
    unsigned short* wvT = (unsigned short*)(ws + 34 * MB);   // 2MB
    unsigned short* vvT = (unsigned short*)(ws + 36 * MB);   // 16MB
    unsigned short* P   = (unsigned short*)(ws + 52 * MB);   // 32MB bf16 exp(s)

    stage1     <<<dim3(4608), 256, 0, stream>>>(x, xb, wv, wvT, wq, wk, Gt);
    proj_gemm  <<<dim3(1024), 256, 0, stream>>>(xb, Gt, wvT, y, vvT);
    scores_gemm<<<dim3(1024), 256, 0, stream>>>(y, xb, P);
    pv_gemm    <<<dim3(512),  256, 0, stream>>>(P, vvT, out);
}

// Round 15
// 155.700 us; speedup vs baseline: 1.6130x; 1.6130x over previous
//
#include <hip/hip_runtime.h>

// B=4, S=2048, D=1024. out = softmax((x@Wk)(x@Wq)^T / 32) @ (x@Wv), fp32 out.
// Algebra: Gt[e,d] = Wq[e,:]·Wk[d,:]; y = x·G (B^T gemm vs Gt); scores = y·x^T.
// GEMM core = measured optimum (r6/r11/r13): 128x128 tiles, 4 waves (2x2), BK=64,
// dbuf 64KB LDS (2 blocks/CU — required; 1-block/CU configs convoy),
// 2-deep counted-vmcnt pipeline, 2 barriers/K-tile, 0-conflict XOR-swizzled LDS,
// XCD swizzle, setprio. scores writes exp(s/32) bf16 P; pv row-sums via ones-MFMA.
// Failed alternatives (do not retry): fine phase-split (r4/r12), 1-block/CU
// (r5/r12), 4-block/CU (r7), wide wave-tile at VGPR=128 (r8), B-in-VGPR (r14).

typedef __attribute__((ext_vector_type(8))) short bf16x8;
typedef __attribute__((ext_vector_type(4))) float f32x4;

__device__ __forceinline__ unsigned short f2bf(float f) {
    unsigned int u = __float_as_uint(f);
    u += 0x7fff + ((u >> 16) & 1);   // RNE
    return (unsigned short)(u >> 16);
}

__device__ __forceinline__ void gld_lds16(const unsigned short* g, unsigned short* l) {
    __builtin_amdgcn_global_load_lds(
        (const __attribute__((address_space(1))) void*)g,
        (__attribute__((address_space(3))) void*)l, 16, 0, 0);
}

template<int N> __device__ __forceinline__ void vmcnt_wait() {
    if constexpr (N == 0) asm volatile("s_waitcnt vmcnt(0)" ::: "memory");
    else if constexpr (N == 8) asm volatile("s_waitcnt vmcnt(8)" ::: "memory");
}
__device__ __forceinline__ void bar() {
    asm volatile("" ::: "memory");
    __builtin_amdgcn_s_barrier();
    asm volatile("" ::: "memory");
}

// ---------------- 128x128x(64*KT) bf16 B^T GEMM, 4 waves (2x2) ----------------
// C[m,n] = sum_k A[bm+m,k]*B[bn+n,k]. Wave tile 64x64: acc[4][4] 16x16 frags.
// LDS per operand: 2 buf x 2 kh x [128 rows][32 bf16]; phys 16B-unit of row r
// holds global unit u ^ ((r>>1)&3) (0 conflicts). Stage: inverse-swizzled
// global src, linear global_load_lds dest. 2-deep counted-vmcnt pipeline.
template<int KT, bool RS>
__device__ __forceinline__ void gemm4(
    const unsigned short* __restrict__ A, const unsigned short* __restrict__ B,
    int lda, int ldb, int bm, int bn,
    unsigned short* As, unsigned short* Bs,
    f32x4 (&acc)[4][4], f32x4 (&os)[4])
{
    const int tid  = threadIdx.x;
    const int lane = tid & 63;
    const int wave = tid >> 6;            // 0..3
    const int wr = wave >> 1, wc = wave & 1;
    const int lr = lane & 15, kg = lane >> 4;

    const bf16x8 ONES = { (short)0x3F80, (short)0x3F80, (short)0x3F80, (short)0x3F80,
                          (short)0x3F80, (short)0x3F80, (short)0x3F80, (short)0x3F80 };

    const int srow = tid >> 2;                       // 0..63
    const int ssrc = ((tid & 3) ^ ((tid >> 3) & 3)) * 8;
    const unsigned short* pa0 = A + (size_t)(bm + srow) * lda + ssrc;
    const unsigned short* pa1 = A + (size_t)(bm + 64 + srow) * lda + ssrc;
    const unsigned short* pb0 = B + (size_t)(bn + srow) * ldb + ssrc;
    const unsigned short* pb1 = B + (size_t)(bn + 64 + srow) * ldb + ssrc;

    const int phys = (kg ^ ((lr >> 1) & 3)) * 8;
    const int aoff = (wr * 64 + lr) * 32 + phys;
    const int boff = (wc * 64 + lr) * 32 + phys;

    auto stage = [&](int buf, int kt) {
        unsigned short* da = As + buf * 8192 + wave * 512;
        unsigned short* db = Bs + buf * 8192 + wave * 512;
        #pragma unroll
        for (int kh = 0; kh < 2; kh++) {
            const int go = kt * 64 + kh * 32;
            gld_lds16(pa0 + go, da + kh * 4096);
            gld_lds16(pa1 + go, da + kh * 4096 + 2048);
            gld_lds16(pb0 + go, db + kh * 4096);
            gld_lds16(pb1 + go, db + kh * 4096 + 2048);
        }
    };

    stage(0, 0);
    stage(1, 1);
    vmcnt_wait<8>();
    bar();

    for (int kt = 0; kt < KT; ++kt) {
        const int c = kt & 1;
        const unsigned short* Ab = As + c * 8192 + aoff;
        const unsigned short* Bb = Bs + c * 8192 + boff;

        #pragma unroll
        for (int kh = 0; kh < 2; kh++) {
            bf16x8 af[4], bf[4];
            #pragma unroll
            for (int mf = 0; mf < 4; mf++)
                af[mf] = *reinterpret_cast<const bf16x8*>(Ab + kh * 4096 + mf * 512);
            #pragma unroll
            for (int nf = 0; nf < 4; nf++)
                bf[nf] = *reinterpret_cast<const bf16x8*>(Bb + kh * 4096 + nf * 512);
            __builtin_amdgcn_s_setprio(1);
            #pragma unroll
            for (int mf = 0; mf < 4; mf++)
                #pragma unroll
                for (int nf = 0; nf < 4; nf++)
                    acc[mf][nf] = __builtin_amdgcn_mfma_f32_16x16x32_bf16(af[mf], bf[nf], acc[mf][nf], 0, 0, 0);
            if constexpr (RS) {
                #pragma unroll
                for (int mf = 0; mf < 4; mf++)
                    os[mf] = __builtin_amdgcn_mfma_f32_16x16x32_bf16(af[mf], ONES, os[mf], 0, 0, 0);
            }
            __builtin_amdgcn_s_setprio(0);
        }

        if (kt == KT - 1) break;
        bar();                     // all waves done reading buf c
        if (kt + 2 < KT) {
            stage(c, kt + 2);      // overwrite buf c with tile kt+2
            vmcnt_wait<8>();       // tile kt+1 (issued a full tile ago) landed
        } else {
            vmcnt_wait<0>();
        }
        bar();                     // buf (kt+1)&1 globally ready
    }
}

// ================ stage 1 (merged): g_gemm | convert_x | transpose_wv ================
// blocks [0,256):      Gt[m,n] = sum_j Wq[m,j]*Wk[n,j]  (64x64 tiles, reg-prefetch)
// blocks [256,4352):   x f32 -> xb bf16
// blocks [4352,4608):  Wv [k][n] f32 -> wvT [n][k] bf16
__global__ __launch_bounds__(256) void stage1(
    const float* __restrict__ x,  unsigned short* __restrict__ xb,
    const float* __restrict__ wv, unsigned short* __restrict__ wvT,
    const float* __restrict__ wq, const float* __restrict__ wk,
    unsigned short* __restrict__ Gt)
{
    __shared__ unsigned short SM[4608];
    const int bid = blockIdx.x;
    const int tid = threadIdx.x;

    if (bid >= 256 && bid < 4352) {
        const size_t idx = (size_t)(bid - 256) * 256 + tid;
        const float4* xi = reinterpret_cast<const float4*>(x) + idx * 2;
        float4 v0 = xi[0], v1 = xi[1];
        ushort4 a = { f2bf(v0.x), f2bf(v0.y), f2bf(v0.z), f2bf(v0.w) };
        ushort4 b = { f2bf(v1.x), f2bf(v1.y), f2bf(v1.z), f2bf(v1.w) };
        ushort4* xo = reinterpret_cast<ushort4*>(xb) + idx * 2;
        xo[0] = a; xo[1] = b;
        return;
    }
    if (bid >= 4352) {
        auto T = reinterpret_cast<unsigned short (*)[72]>(SM);
        const int tb = bid - 4352;
        const int k0 = (tb >> 4) * 64, n0 = (tb & 15) * 64;
        const int r = tid >> 4, c4 = (tid & 15) * 4;
        #pragma unroll
        for (int i = 0; i < 4; i++) {
            int kr = r + i * 16;
            float4 v = *reinterpret_cast<const float4*>(&wv[(size_t)(k0 + kr) * 1024 + n0 + c4]);
            T[c4 + 0][kr] = f2bf(v.x);
            T[c4 + 1][kr] = f2bf(v.y);
            T[c4 + 2][kr] = f2bf(v.z);
            T[c4 + 3][kr] = f2bf(v.w);
        }
        __syncthreads();
        #pragma unroll
        for (int i = 0; i < 4; i++) {
            int n = r + i * 16;
            ushort4 v = *reinterpret_cast<const ushort4*>(&T[n][c4]);
            *reinterpret_cast<ushort4*>(&wvT[(size_t)(n0 + n) * 1024 + k0 + c4]) = v;
        }
        return;
    }

    // g_gemm: 64x64 tile, BK=32, reg-prefetch pipelined, f32->bf16 in staging
    unsigned short* As = SM;
    unsigned short* Bs = SM + 2048;
    const int gb = bid;
    const int bm = (gb >> 4) * 64, bn = (gb & 15) * 64;

    const int lane = tid & 63;
    const int wave = tid >> 6;
    const int wr = wave >> 1, wc = wave & 1;
    const int lr = lane & 15, kg = lane >> 4;

    const int srow = tid >> 2;
    const int su   = tid & 3;
    const int sphys = (su ^ ((srow >> 1) & 3)) * 8;
    const int rphys = (kg ^ ((lr >> 1) & 3)) * 8;
    const int aoff = (wr * 32 + lr) * 32 + rphys;
    const int boff = (wc * 32 + lr) * 32 + rphys;

    const float* pa = &wq[(size_t)(bm + srow) * 1024 + su * 8];
    const float* pb = &wk[(size_t)(bn + srow) * 1024 + su * 8];

    f32x4 acc[2][2] = {};

    float4 a0 = *reinterpret_cast<const float4*>(pa);
    float4 a1 = *reinterpret_cast<const float4*>(pa + 4);
    float4 b0 = *reinterpret_cast<const float4*>(pb);
    float4 b1 = *reinterpret_cast<const float4*>(pb + 4);

    for (int k0 = 0; k0 < 1024; k0 += 32) {
        ushort4 u0 = { f2bf(a0.x), f2bf(a0.y), f2bf(a0.z), f2bf(a0.w) };
        ushort4 u1 = { f2bf(a1.x), f2bf(a1.y), f2bf(a1.z), f2bf(a1.w) };
        *reinterpret_cast<ushort4*>(&As[srow * 32 + sphys])     = u0;
        *reinterpret_cast<ushort4*>(&As[srow * 32 + sphys + 4]) = u1;
        ushort4 t0 = { f2bf(b0.x), f2bf(b0.y), f2bf(b0.z), f2bf(b0.w) };
        ushort4 t1 = { f2bf(b1.x), f2bf(b1.y), f2bf(b1.z), f2bf(b1.w) };
        *reinterpret_cast<ushort4*>(&Bs[srow * 32 + sphys])     = t0;
        *reinterpret_cast<ushort4*>(&Bs[srow * 32 + sphys + 4]) = t1;

        if (k0 + 32 < 1024) {
            const float* npa = pa + k0 + 32;
            const float* npb = pb + k0 + 32;
            a0 = *reinterpret_cast<const float4*>(npa);
            a1 = *reinterpret_cast<const float4*>(npa + 4);
            b0 = *reinterpret_cast<const float4*>(npb);
            b1 = *reinterpret_cast<const float4*>(npb + 4);
        }
        __syncthreads();

        bf16x8 af[2], bf[2];
        #pragma unroll
        for (int mf = 0; mf < 2; mf++)
            af[mf] = *reinterpret_cast<const bf16x8*>(&As[aoff + mf * 512]);
        #pragma unroll
        for (int nf = 0; nf < 2; nf++)
            bf[nf] = *reinterpret_cast<const bf16x8*>(&Bs[boff + nf * 512]);
        #pragma unroll
        for (int mf = 0; mf < 2; mf++)
            #pragma unroll
            for (int nf = 0; nf < 2; nf++)
                acc[mf][nf] = __builtin_amdgcn_mfma_f32_16x16x32_bf16(af[mf], bf[nf], acc[mf][nf], 0, 0, 0);
        __syncthreads();
    }
    #pragma unroll
    for (int mf = 0; mf < 2; mf++)
        #pragma unroll
        for (int nf = 0; nf < 2; nf++)
            #pragma unroll
            for (int r = 0; r < 4; r++)
                Gt[(size_t)(bm + wr * 32 + mf * 16 + kg * 4 + r) * 1024
                   + bn + wc * 32 + nf * 16 + lr] = f2bf(acc[mf][nf][r]);
}

// ---------------- projections: z=0: y = x·G; z=1: vvT (transposed). grid 1024 ----------------
__global__ __launch_bounds__(256, 2) void proj_gemm(
    const unsigned short* __restrict__ xb, const unsigned short* __restrict__ Gt,
    const unsigned short* __restrict__ wvT,
    unsigned short* __restrict__ y, unsigned short* __restrict__ vvT)
{
    __shared__ unsigned short As[2 * 128 * 64], Bs[2 * 128 * 64];   // 64 KB
    const int bid = blockIdx.x;
    const int wg  = (bid & 7) * 128 + (bid >> 3);   // 1024 % 8 == 0, bijective
    const int z   = wg >> 9;
    const int rem = wg & 511;
    const int bm  = (rem >> 3) * 128;
    const int bn  = (rem & 7) * 128;
    const unsigned short* Bw = z ? wvT : Gt;

    f32x4 acc[4][4] = {};
    f32x4 os[4] = {};
    gemm4<16, false>(xb, Bw, 1024, 1024, bm, bn, As, Bs, acc, os);

    const int tid = threadIdx.x, lane = tid & 63, wave = tid >> 6;
    const int wr = wave >> 1, wc = wave & 1, lr = lane & 15, kg = lane >> 4;
    if (z == 0) {
        #pragma unroll
        for (int mf = 0; mf < 4; mf++)
            #pragma unroll
            for (int nf = 0; nf < 4; nf++)
                #pragma unroll
                for (int r = 0; r < 4; r++)
                    y[(size_t)(bm + wr * 64 + mf * 16 + kg * 4 + r) * 1024
                      + bn + wc * 64 + nf * 16 + lr] = f2bf(acc[mf][nf][r]);
    } else {
        const int batch = bm >> 11;                 // 128-tiles never span batches
        unsigned short* o = vvT + (size_t)batch * 1024 * 2048;
        #pragma unroll
        for (int mf = 0; mf < 4; mf++)
            #pragma unroll
            for (int nf = 0; nf < 4; nf++) {
                ushort4 v = { f2bf(acc[mf][nf][0]), f2bf(acc[mf][nf][1]),
                              f2bf(acc[mf][nf][2]), f2bf(acc[mf][nf][3]) };
                *reinterpret_cast<ushort4*>(
                    &o[(size_t)(bn + wc * 64 + nf * 16 + lr) * 2048
                       + (bm & 2047) + wr * 64 + mf * 16 + kg * 4]) = v;
            }
    }
}

// ---------------- scores: y[b]·xb[b]^T / 32, exp epilogue -> bf16 P. grid 1024 ----------------
__global__ __launch_bounds__(256, 2) void scores_gemm(
    const unsigned short* __restrict__ y, const unsigned short* __restrict__ xb,
    unsigned short* __restrict__ P)
{
    __shared__ unsigned short As[2 * 128 * 64], Bs[2 * 128 * 64];   // 64 KB
    const int bid = blockIdx.x;
    const int wg  = (bid & 7) * 128 + (bid >> 3);   // 1024 % 8 == 0
    const int z   = wg >> 8;
    const int rem = wg & 255;
    const int bm  = (rem >> 4) * 128;
    const int bn  = (rem & 15) * 128;
    const unsigned short* A = y  + (size_t)z * 2048 * 1024;
    const unsigned short* B = xb + (size_t)z * 2048 * 1024;
    unsigned short* out = P + (size_t)z * 2048 * 2048;

    f32x4 acc[4][4] = {};
    f32x4 os[4] = {};
    gemm4<16, false>(A, B, 1024, 1024, bm, bn, As, Bs, acc, os);

    const int tid = threadIdx.x, lane = tid & 63, wave = tid >> 6;
    const int wr = wave >> 1, wc = wave & 1, lr = lane & 15, kg = lane >> 4;
    #pragma unroll
    for (int mf = 0; mf < 4; mf++)
        #pragma unroll
        for (int nf = 0; nf < 4; nf++)
            #pragma unroll
            for (int r = 0; r < 4; r++)
                out[(size_t)(bm + wr * 64 + mf * 16 + kg * 4 + r) * 2048
                    + bn + wc * 64 + nf * 16 + lr]
                    = f2bf(__expf(acc[mf][nf][r] * 0.03125f));
}

// ---------------- PV: 128x128 tiles, K=2048, grid 512; ones-MFMA row-sums; out = acc/l ----------------
__global__ __launch_bounds__(256, 2) void pv_gemm(
    const unsigned short* __restrict__ P, const unsigned short* __restrict__ vvT,
    float* __restrict__ out)
{
    __shared__ unsigned short As[2 * 128 * 64], Bs[2 * 128 * 64];   // 64 KB
    const int bid = blockIdx.x;
    const int wg  = (bid & 7) * 64 + (bid >> 3);    // 512 % 8 == 0
    const int z   = wg >> 7;
    const int rem = wg & 127;
    const int bm  = (rem >> 3) * 128;
    const int bn  = (rem & 7) * 128;
    const unsigned short* A = P   + (size_t)z * 2048 * 2048;
    const unsigned short* B = vvT + (size_t)z * 1024 * 2048;
    float* o = out + (size_t)z * 2048 * 1024;

    f32x4 acc[4][4] = {};
    f32x4 os[4] = {};
    gemm4<32, true>(A, B, 2048, 2048, bm, bn, As, Bs, acc, os);

    const int tid = threadIdx.x, lane = tid & 63, wave = tid >> 6;
    const int wr = wave >> 1, wc = wave & 1, lr = lane & 15, kg = lane >> 4;

    // os[mf][r] = full row-sum for row (bm + wr*64 + mf*16 + kg*4 + r), lane-replicated.
    #pragma unroll
    for (int mf = 0; mf < 4; mf++)
        #pragma unroll
        for (int r = 0; r < 4; r++) {
            const float inv = 1.0f / os[mf][r];
            #pragma unroll
            for (int nf = 0; nf < 4; nf++)
                o[(size_t)(bm + wr * 64 + mf * 16 + kg * 4 + r) * 1024
                  + bn + wc * 64 + nf * 16 + lr] = acc[mf][nf][r] * inv;
        }
}

extern "C" void kernel_launch(void* const* d_in, const int* in_sizes, int n_in,
                              void* d_out, int out_size, void* d_ws, size_t ws_size,
                              hipStream_t stream) {
    const float* x  = (const float*)d_in[0];
    const float* wk = (const float*)d_in[1];
    const float* wq = (const float*)d_in[2];
    const float* wv = (const float*)d_in[3];
    float* out = (float*)d_out;

    char* ws = (char*)d_ws;
    const size_t MB = 1024 * 1024;
    unsigned short* xb  = (unsigned short*)(ws);             // 16MB  x bf16
    unsigned short* y   = (unsigned short*)(ws + 16 * MB);   // 16MB  x·G bf16
    unsigned short* Gt  = (unsigned short*)(ws + 32 * MB);   // 2MB   Gt[e,d]
    unsigned short* wvT = (unsigned short*)(ws + 34 * MB);   // 2MB
    unsigned short* vvT = (unsigned short*)(ws + 36 * MB);   // 16MB
    unsigned short* P   = (unsigned short*)(ws + 52 * MB);   // 32MB bf16 exp(s)

    stage1     <<<dim3(4608), 256, 0, stream>>>(x, xb, wv, wvT, wq, wk, Gt);
    proj_gemm  <<<dim3(1024), 256, 0, stream>>>(xb, Gt, wvT, y, vvT);
    scores_gemm<<<dim3(1024), 256, 0, stream>>>(y, xb, P);
    pv_gemm    <<<dim3(512),  256, 0, stream>>>(P, vvT, out);
}